// Round 3
// baseline (298.537 us; speedup 1.0000x reference)
//
#include <hip/hip_runtime.h>

#define NB 2048
#define NM 128
#define ND 5
#define NFA 62
#define NFB 6
#define NFAN 68
#define NC 128
#define KP 96       // padded K for MFMA (3 x 32)
#define LDA 104     // bf16 row stride for s_A: 208 B -> 2-way (free) conflict pattern, 16B aligned
#define LDSF 72     // fp32 row stride for s_sf
#define CHUNK 16

typedef __bf16 bf16x8 __attribute__((ext_vector_type(8)));
typedef float floatx4 __attribute__((ext_vector_type(4)));

__device__ __forceinline__ unsigned short f2bf(float x) {
    unsigned u = __builtin_bit_cast(unsigned, x);
    u += 0x7FFFu + ((u >> 16) & 1u);   // RNE
    return (unsigned short)(u >> 16);
}

// Pack W_self (68x128 fp32, k-major) -> ws as bf16 [c][96] (c-major, K zero-padded).
__global__ __launch_bounds__(256) void prep_w(const float* __restrict__ W_self,
                                              unsigned short* __restrict__ wsb) {
    const int i = blockIdx.x * 256 + threadIdx.x;   // i < 128*96
    const int c = i / KP;
    const int f = i - c * KP;
    unsigned short v = 0;
    if (f < NFAN) v = f2bf(W_self[f * NC + c]);
    wsb[i] = v;
}

__global__ __launch_bounds__(256, 4) void tga_mfma(
    const float* __restrict__ atoms,
    const float* __restrict__ bonds,
    const int*   __restrict__ edges,
    const float* __restrict__ W_inner,
    const float* __restrict__ b_inner,
    const float* __restrict__ b_self,
    const unsigned short* __restrict__ wsb,
    float* __restrict__ out)
{
    __shared__ __align__(16) unsigned short s_A[NM * LDA];  // vxi rows in bf16, K-padded
    __shared__ __align__(16) float s_sf[CHUNK * LDSF];      // summed features, listed rows only
    __shared__ int s_list[NM];
    __shared__ int s_nlist;

    const int tid = threadIdx.x;
    const int b   = blockIdx.x;
    if (tid == 0) s_nlist = 0;

    const float* atoms_b = atoms + (size_t)b * (NM * NFA);
    const int*   edges_b = edges + (size_t)b * (NM * ND);
    const float* bonds_b = bonds + (size_t)b * (NM * ND * NFB);
    float*       out_b   = out   + (size_t)b * (NM * NC);

    // ---- Phase 0: atoms -> s_A bf16 (cols 0..61), coalesced float2 reads ----
    for (int i = tid; i < NM * 31; i += 256) {
        int m = i / 31, p = i - m * 31;
        float2 v = *(const float2*)&atoms_b[m * NFA + 2 * p];
        unsigned pack = (unsigned)f2bf(v.x) | ((unsigned)f2bf(v.y) << 16);
        *(unsigned*)&s_A[m * LDA + 2 * p] = pack;
    }
    // zero K-pad region s_A[m][68..95]
    for (int i = tid; i < NM * 7; i += 256) {
        int m = i / 7, q = i - m * 7;
        *(unsigned long long*)&s_A[m * LDA + 68 + 4 * q] = 0ULL;
    }

    // ---- Phase 1: degree/list + bond sums (bf16 into s_A cols 62..67) ----
    {
        const int m = tid >> 1, half = tid & 1;
        if (half == 0) {
            const int* e = edges_b + m * ND;
            int deg = 0;
            #pragma unroll
            for (int j = 0; j < ND; ++j) deg += (e[j] >= 0);
            if (deg < ND) {
                int slot = atomicAdd(&s_nlist, 1);
                s_list[slot] = m | (deg << 16);
            }
        } else {
            const float* bp = bonds_b + m * (ND * NFB);
            float sb[NFB] = {0.f, 0.f, 0.f, 0.f, 0.f, 0.f};
            #pragma unroll
            for (int p = 0; p < 15; ++p) {
                float2 v = *(const float2*)&bp[2 * p];
                sb[(2 * p) % NFB]     += v.x;
                sb[(2 * p + 1) % NFB] += v.y;
            }
            *(unsigned*)&s_A[m * LDA + 62] = (unsigned)f2bf(sb[0]) | ((unsigned)f2bf(sb[1]) << 16);
            *(unsigned*)&s_A[m * LDA + 64] = (unsigned)f2bf(sb[2]) | ((unsigned)f2bf(sb[3]) << 16);
            *(unsigned*)&s_A[m * LDA + 66] = (unsigned)f2bf(sb[4]) | ((unsigned)f2bf(sb[5]) << 16);
        }
    }
    __syncthreads();

    // ---- Phase 2: zxi = relu(vxi @ W_self + b_self) via MFMA 16x16x32 bf16,
    //      B-fragments straight from L1-resident prepacked weights ----
    {
        const int lane = tid & 63;
        const int wave = tid >> 6;
        const int col  = lane & 15;
        const int quad = lane >> 4;
        const int m0   = wave * 32;

        floatx4 acc[16];
        #pragma unroll
        for (int t = 0; t < 16; ++t) { floatx4 z; z[0]=z[1]=z[2]=z[3]=0.f; acc[t] = z; }

        const unsigned short* wb = wsb + col * KP + quad * 8;

        #pragma unroll
        for (int k = 0; k < 3; ++k) {
            const int koff = k * 32 + quad * 8;
            bf16x8 a0 = *(const bf16x8*)&s_A[(m0 + col) * LDA + koff];
            bf16x8 a1 = *(const bf16x8*)&s_A[(m0 + 16 + col) * LDA + koff];
            #pragma unroll
            for (int nt = 0; nt < 8; ++nt) {
                bf16x8 bf = *(const bf16x8*)&wb[nt * 16 * KP + k * 32];
                acc[nt]     = __builtin_amdgcn_mfma_f32_16x16x32_bf16(a0, bf, acc[nt],     0, 0, 0);
                acc[8 + nt] = __builtin_amdgcn_mfma_f32_16x16x32_bf16(a1, bf, acc[8 + nt], 0, 0, 0);
            }
        }

        // epilogue: C layout col=lane&15, row=quad*4+reg
        #pragma unroll
        for (int nt = 0; nt < 8; ++nt) {
            const float bias = b_self[nt * 16 + col];
            #pragma unroll
            for (int r = 0; r < 4; ++r) {
                const int row0 = m0 + quad * 4 + r;
                out_b[row0 * NC + nt * 16 + col]        = fmaxf(acc[nt][r]     + bias, 0.0f);
                out_b[(row0 + 16) * NC + nt * 16 + col] = fmaxf(acc[8 + nt][r] + bias, 0.0f);
            }
        }
    }
    __syncthreads();

    // ---- Phase 3: zni for rows with deg<5 (~5/block), fp32, chunked ----
    const int nl = s_nlist;
    const int c  = tid & 127;
    const int rg = tid >> 7;

    for (int base = 0; base < nl; base += CHUNK) {
        if (tid < 2 * CHUNK) {
            const int r = tid >> 1, half = tid & 1;
            if (base + r < nl) {
                const int m = s_list[base + r] & 0xFFFF;
                const int* e = edges_b + m * ND;
                int ev[ND];
                #pragma unroll
                for (int j = 0; j < ND; ++j) ev[j] = e[j];

                if (half == 0) {
                    float v[32];
                    #pragma unroll
                    for (int j = 0; j < 32; ++j) v[j] = 0.f;
                    #pragma unroll
                    for (int j = 0; j < ND; ++j) {
                        if (ev[j] >= 0) {
                            const float* ap = atoms_b + ev[j] * NFA;
                            #pragma unroll
                            for (int p = 0; p < 16; ++p) {
                                float2 t = *(const float2*)&ap[2 * p];
                                v[2 * p] += t.x; v[2 * p + 1] += t.y;
                            }
                        }
                    }
                    #pragma unroll
                    for (int q = 0; q < 8; ++q)
                        *(float4*)&s_sf[r * LDSF + 4 * q] = make_float4(v[4*q], v[4*q+1], v[4*q+2], v[4*q+3]);
                } else {
                    float v[36];  // features 32..67
                    #pragma unroll
                    for (int j = 0; j < 30; ++j) v[j] = 0.f;
                    #pragma unroll
                    for (int j = 0; j < ND; ++j) {
                        if (ev[j] >= 0) {
                            const float* ap = atoms_b + ev[j] * NFA;
                            #pragma unroll
                            for (int p = 0; p < 15; ++p) {
                                float2 t = *(const float2*)&ap[32 + 2 * p];
                                v[2 * p] += t.x; v[2 * p + 1] += t.y;
                            }
                        }
                    }
                    const float* bp = bonds_b + m * (ND * NFB);
                    float sb[NFB] = {0.f, 0.f, 0.f, 0.f, 0.f, 0.f};
                    #pragma unroll
                    for (int p = 0; p < 15; ++p) {
                        float2 t = *(const float2*)&bp[2 * p];
                        sb[(2 * p) % NFB]     += t.x;
                        sb[(2 * p + 1) % NFB] += t.y;
                    }
                    #pragma unroll
                    for (int j = 0; j < NFB; ++j) v[30 + j] = sb[j];
                    #pragma unroll
                    for (int q = 0; q < 9; ++q)
                        *(float4*)&s_sf[r * LDSF + 32 + 4 * q] = make_float4(v[4*q], v[4*q+1], v[4*q+2], v[4*q+3]);
                }
            }
        }
        __syncthreads();

        const int nrows = min(nl - base, CHUNK);
        for (int r = rg; r < nrows; r += 2) {
            const int packed = s_list[base + r];
            const int m = packed & 0xFFFF;
            const int d = packed >> 16;
            const float* Wd = W_inner + (size_t)d * (NFAN * NC) + c;
            float acc1 = b_inner[d * NC + c];
            #pragma unroll
            for (int q = 0; q < 17; ++q) {
                float4 v = *(const float4*)&s_sf[r * LDSF + 4 * q];
                acc1 += v.x * Wd[(4 * q) * NC] + v.y * Wd[(4 * q + 1) * NC]
                      + v.z * Wd[(4 * q + 2) * NC] + v.w * Wd[(4 * q + 3) * NC];
            }
            out_b[m * NC + c] += fmaxf(acc1, 0.0f);
        }
        __syncthreads();
    }
}

extern "C" void kernel_launch(void* const* d_in, const int* in_sizes, int n_in,
                              void* d_out, int out_size, void* d_ws, size_t ws_size,
                              hipStream_t stream) {
    const float* atoms   = (const float*)d_in[0];
    const float* bonds   = (const float*)d_in[1];
    const int*   edges   = (const int*)d_in[2];
    const float* W_inner = (const float*)d_in[3];
    const float* b_inner = (const float*)d_in[4];
    const float* W_self  = (const float*)d_in[5];
    const float* b_self  = (const float*)d_in[6];
    float* out = (float*)d_out;
    unsigned short* wsb = (unsigned short*)d_ws;   // 128*96*2 = 24.6 KB

    prep_w<<<(NC * KP + 255) / 256, 256, 0, stream>>>(W_self, wsb);
    tga_mfma<<<NB, 256, 0, stream>>>(atoms, bonds, edges, W_inner, b_inner,
                                     b_self, wsb, out);
}

// Round 4
// 264.191 us; speedup vs baseline: 1.1300x; 1.1300x over previous
//
#include <hip/hip_runtime.h>

#define NB 2048
#define NM 128
#define ND 5
#define NFA 62
#define NFB 6
#define NFAN 68
#define NC 128
#define KP 96       // padded K for MFMA (3 x 32)

typedef __bf16 bf16x8 __attribute__((ext_vector_type(8)));
typedef float floatx4 __attribute__((ext_vector_type(4)));

__device__ __forceinline__ unsigned short f2bf(float x) {
    unsigned u = __builtin_bit_cast(unsigned, x);
    u += 0x7FFFu + ((u >> 16) & 1u);   // RNE
    return (unsigned short)(u >> 16);
}

// Pack W_self (68x128 fp32, k-major) -> wsb as bf16 [c][96] (c-major, K zero-padded).
__global__ __launch_bounds__(256) void prep_w(const float* __restrict__ W_self,
                                              unsigned short* __restrict__ wsb) {
    const int i = blockIdx.x * 256 + threadIdx.x;   // i < 128*96
    const int c = i / KP;
    const int f = i - c * KP;
    unsigned short v = 0;
    if (f < NFAN) v = f2bf(W_self[f * NC + c]);
    wsb[i] = v;
}

__device__ __forceinline__ bf16x8 load8(const float* p) {
    float2 v0 = *(const float2*)(p);
    float2 v1 = *(const float2*)(p + 2);
    float2 v2 = *(const float2*)(p + 4);
    float2 v3 = *(const float2*)(p + 6);
    bf16x8 r;
    r[0] = (__bf16)v0.x; r[1] = (__bf16)v0.y; r[2] = (__bf16)v1.x; r[3] = (__bf16)v1.y;
    r[4] = (__bf16)v2.x; r[5] = (__bf16)v2.y; r[6] = (__bf16)v3.x; r[7] = (__bf16)v3.y;
    return r;
}

// floats p[0..5] (atoms features 56..61) + bond sums bs[0],bs[1] (features 62,63)
__device__ __forceinline__ bf16x8 load6bs(const float* p, const float* bs) {
    float2 v0 = *(const float2*)(p);
    float2 v1 = *(const float2*)(p + 2);
    float2 v2 = *(const float2*)(p + 4);
    float2 b01 = *(const float2*)(bs);
    bf16x8 r;
    r[0] = (__bf16)v0.x; r[1] = (__bf16)v0.y; r[2] = (__bf16)v1.x; r[3] = (__bf16)v1.y;
    r[4] = (__bf16)v2.x; r[5] = (__bf16)v2.y; r[6] = (__bf16)b01.x; r[7] = (__bf16)b01.y;
    return r;
}

__global__ __launch_bounds__(256) void tga_wave(
    const float* __restrict__ atoms,
    const float* __restrict__ bonds,
    const int*   __restrict__ edges,
    const float* __restrict__ W_inner,
    const float* __restrict__ b_inner,
    const float* __restrict__ b_self,
    const unsigned short* __restrict__ wsb,
    float* __restrict__ out)
{
    // Wave-private LDS only (no __syncthreads in this kernel).
    __shared__ __align__(16) float s_bsf[4][32][8];  // per row: [bs2,bs3,bs4,bs5, bs0,bs1, -, -]
    __shared__ float s_sf[4][64];                    // sparse-path summed-atom features

    const int tid  = threadIdx.x;
    const int w    = tid >> 6;
    const int lane = tid & 63;
    const int b    = blockIdx.x;
    const int m0   = w * 32;      // this wave owns rows m0..m0+31

    const float* atoms_b = atoms + (size_t)b * (NM * NFA);
    const float* bonds_b = bonds + (size_t)b * (NM * ND * NFB);
    const int*   edges_b = edges + (size_t)b * (NM * ND);
    float*       out_b   = out   + (size_t)b * (NM * NC);

    // ---- edges + degree (lanes 0..31, one row each) ----
    int E0 = -1, E1 = -1, E2 = -1, E3 = -1, E4 = -1, deg = ND;
    if (lane < 32) {
        const int* e = edges_b + (m0 + lane) * ND;
        E0 = e[0]; E1 = e[1]; E2 = e[2]; E3 = e[3]; E4 = e[4];
        deg = (E0 >= 0) + (E1 >= 0) + (E2 >= 0) + (E3 >= 0) + (E4 >= 0);
    }
    unsigned long long smask = __ballot((lane < 32) && (deg < ND));

    // ---- bond sums: 2 lanes per row, combine via shfl_xor ----
    {
        const int rb = lane >> 1, half = lane & 1;
        const float* bp = bonds_b + (m0 + rb) * (ND * NFB);
        float sb[NFB] = {0.f, 0.f, 0.f, 0.f, 0.f, 0.f};
        if (half == 0) {
            #pragma unroll
            for (int p = 0; p < 8; ++p) {
                float2 v = *(const float2*)&bp[2 * p];
                sb[(2 * p) % NFB]     += v.x;
                sb[(2 * p + 1) % NFB] += v.y;
            }
        } else {
            #pragma unroll
            for (int p = 8; p < 15; ++p) {
                float2 v = *(const float2*)&bp[2 * p];
                sb[(2 * p) % NFB]     += v.x;
                sb[(2 * p + 1) % NFB] += v.y;
            }
        }
        #pragma unroll
        for (int j = 0; j < NFB; ++j) sb[j] += __shfl_xor(sb[j], 1);
        if (half == 0) {
            *(float4*)&s_bsf[w][rb][0] = make_float4(sb[2], sb[3], sb[4], sb[5]);
            *(float2*)&s_bsf[w][rb][4] = make_float2(sb[0], sb[1]);
        }
    }
    __builtin_amdgcn_wave_barrier();

    // ---- build A-fragments (vxi) directly from global, MFMA A-layout ----
    const int col = lane & 15, quad = lane >> 4;
    const int lr0 = col, lr1 = 16 + col;          // wave-local rows
    const float* p0 = atoms_b + (m0 + lr0) * NFA;
    const float* p1 = atoms_b + (m0 + lr1) * NFA;

    bf16x8 a00 = load8(p0 + quad * 8);
    bf16x8 a10 = load8(p1 + quad * 8);
    bf16x8 a01, a11;
    if (quad < 3) {
        a01 = load8(p0 + 32 + quad * 8);
        a11 = load8(p1 + 32 + quad * 8);
    } else {
        a01 = load6bs(p0 + 56, &s_bsf[w][lr0][4]);
        a11 = load6bs(p1 + 56, &s_bsf[w][lr1][4]);
    }
    bf16x8 a02, a12;
    #pragma unroll
    for (int j = 0; j < 8; ++j) { a02[j] = (__bf16)0.f; a12[j] = (__bf16)0.f; }
    if (quad == 0) {
        float4 q0 = *(const float4*)&s_bsf[w][lr0][0];
        float4 q1 = *(const float4*)&s_bsf[w][lr1][0];
        a02[0] = (__bf16)q0.x; a02[1] = (__bf16)q0.y; a02[2] = (__bf16)q0.z; a02[3] = (__bf16)q0.w;
        a12[0] = (__bf16)q1.x; a12[1] = (__bf16)q1.y; a12[2] = (__bf16)q1.z; a12[3] = (__bf16)q1.w;
    }

    // ---- MFMA: stream W fragments from L1-resident wsb ----
    floatx4 acc[16];
    #pragma unroll
    for (int t = 0; t < 16; ++t) { floatx4 z; z[0] = z[1] = z[2] = z[3] = 0.f; acc[t] = z; }

    const unsigned short* wbase = wsb + (size_t)col * KP + quad * 8;
    #pragma unroll
    for (int ct = 0; ct < 8; ++ct) {
        bf16x8 wf0 = *(const bf16x8*)(wbase + ct * 16 * KP);
        bf16x8 wf1 = *(const bf16x8*)(wbase + ct * 16 * KP + 32);
        bf16x8 wf2 = *(const bf16x8*)(wbase + ct * 16 * KP + 64);
        acc[ct]     = __builtin_amdgcn_mfma_f32_16x16x32_bf16(a00, wf0, acc[ct],     0, 0, 0);
        acc[8 + ct] = __builtin_amdgcn_mfma_f32_16x16x32_bf16(a10, wf0, acc[8 + ct], 0, 0, 0);
        acc[ct]     = __builtin_amdgcn_mfma_f32_16x16x32_bf16(a01, wf1, acc[ct],     0, 0, 0);
        acc[8 + ct] = __builtin_amdgcn_mfma_f32_16x16x32_bf16(a11, wf1, acc[8 + ct], 0, 0, 0);
        acc[ct]     = __builtin_amdgcn_mfma_f32_16x16x32_bf16(a02, wf2, acc[ct],     0, 0, 0);
        acc[8 + ct] = __builtin_amdgcn_mfma_f32_16x16x32_bf16(a12, wf2, acc[8 + ct], 0, 0, 0);
    }

    // ---- epilogue: bias + relu, coalesced dword stores (64B segments) ----
    #pragma unroll
    for (int ct = 0; ct < 8; ++ct) {
        const float bias = b_self[ct * 16 + col];
        #pragma unroll
        for (int rr = 0; rr < 4; ++rr) {
            const int row0 = m0 + quad * 4 + rr;
            out_b[row0 * NC + ct * 16 + col]        = fmaxf(acc[ct][rr]     + bias, 0.f);
            out_b[(row0 + 16) * NC + ct * 16 + col] = fmaxf(acc[8 + ct][rr] + bias, 0.f);
        }
    }

    // ---- sparse path: rows with deg<5 (~1.2/wave), whole wave cooperates ----
    while (smask) {
        const int ml = __ffsll(smask) - 1;
        smask &= smask - 1;
        const int m  = m0 + ml;
        const int d  = __shfl(deg, ml);
        const int e0 = __shfl(E0, ml), e1 = __shfl(E1, ml), e2 = __shfl(E2, ml),
                  e3 = __shfl(E3, ml), e4 = __shfl(E4, ml);

        if (lane < NFA) {   // coalesced 248B gathers per neighbor
            float sv = 0.f;
            if (e0 >= 0) sv += atoms_b[e0 * NFA + lane];
            if (e1 >= 0) sv += atoms_b[e1 * NFA + lane];
            if (e2 >= 0) sv += atoms_b[e2 * NFA + lane];
            if (e3 >= 0) sv += atoms_b[e3 * NFA + lane];
            if (e4 >= 0) sv += atoms_b[e4 * NFA + lane];
            s_sf[w][lane] = sv;
        }
        __builtin_amdgcn_wave_barrier();

        const int c0 = 2 * lane;
        float2 bi = *(const float2*)&b_inner[d * NC + c0];
        float acc0 = bi.x, acc1 = bi.y;
        const float* Wd = W_inner + (size_t)d * (NFAN * NC);
        #pragma unroll
        for (int f = 0; f < NFA; ++f) {
            const float sfv = s_sf[w][f];
            float2 wv = *(const float2*)&Wd[f * NC + c0];
            acc0 += sfv * wv.x; acc1 += sfv * wv.y;
        }
        {
            const float* bb = &s_bsf[w][ml][0];
            const float fv[6] = {bb[4], bb[5], bb[0], bb[1], bb[2], bb[3]}; // bs0..bs5
            #pragma unroll
            for (int j = 0; j < NFB; ++j) {
                float2 wv = *(const float2*)&Wd[(NFA + j) * NC + c0];
                acc0 += fv[j] * wv.x; acc1 += fv[j] * wv.y;
            }
        }
        float2 cur = *(float2*)&out_b[m * NC + c0];
        cur.x += fmaxf(acc0, 0.f);
        cur.y += fmaxf(acc1, 0.f);
        *(float2*)&out_b[m * NC + c0] = cur;
        __builtin_amdgcn_wave_barrier();
    }
}

extern "C" void kernel_launch(void* const* d_in, const int* in_sizes, int n_in,
                              void* d_out, int out_size, void* d_ws, size_t ws_size,
                              hipStream_t stream) {
    const float* atoms   = (const float*)d_in[0];
    const float* bonds   = (const float*)d_in[1];
    const int*   edges   = (const int*)d_in[2];
    const float* W_inner = (const float*)d_in[3];
    const float* b_inner = (const float*)d_in[4];
    const float* W_self  = (const float*)d_in[5];
    const float* b_self  = (const float*)d_in[6];
    float* out = (float*)d_out;
    unsigned short* wsb = (unsigned short*)d_ws;   // 128*96*2 = 24.6 KB

    prep_w<<<(NC * KP + 255) / 256, 256, 0, stream>>>(W_self, wsb);
    tga_wave<<<NB, 256, 0, stream>>>(atoms, bonds, edges, W_inner, b_inner,
                                     b_self, wsb, out);
}